// Round 10
// baseline (195.388 us; speedup 1.0000x reference)
//
#include <hip/hip_runtime.h>

// ValueDVHLoss via the Wasserstein/CDF identity.
// R10: invariant found across R5-R9 -- duration tracks LDS-atomic lane-op
// count (~25.2M -> ~55-60us) regardless of loads/bins/banks/occupancy.
// Cut it 3x: pack all 6 ROIs into one 64-bit atomic (10-bit fields,
// a = sum mask_r<<10r; one u64 atomic to pred-hist[bp], one to tgt-hist[bg]).
// 2 atomics/voxel (was 6). Hist 2x1024xu64 = 16KB; LDS 30KB -> 4 blocks/CU
// (grid 1024, DMA staging unchanged from R9 which passed absmax 0.0).

#define NBINS 1024
#define NB1   (NBINS - 1)
#define RROI  6
#define BPAT  4
#define NSEG  24
#define VVOX  1048576            // voxels per patient (C=1)
#define BLKP  256                // hist blocks per patient
#define GRID1 (BPAT * BLKP)      // 1024 blocks = 4/CU
#define CHUNK (VVOX / BLKP)      // 4096 voxels per block
#define TILE  1024               // voxels per DMA tile
#define NTILE (CHUNK / TILE)     // 4
#define HW    (NBINS / 2)        // 512 packed words per (block,roi)

// tile[] int layout: pred 0..1023, tgt 1024..2047, masks 2048..3583
// (6 rois x 256 ints), counts 3584..3589
#define T_PRED 0
#define T_TGT  1024
#define T_MSK  2048
#define T_CNT  3584

// ws layout (int indices)
#define PART_I 0
#define PART_N (GRID1 * RROI * HW)        // 3,145,728 ints (12.6 MB)
#define CNT6_I (PART_I + PART_N)
#define CNT6_N (GRID1 * RROI)             // 6144
#define FH_I   (CNT6_I + CNT6_N)
#define FH_N   (NSEG * NBINS)             // 24576
#define DONE_I (FH_I + FH_N)              // 24
#define SEGD_I (DONE_I + NSEG)            // 1
#define ZERO_I FH_I
#define ZERO_N (FH_N + NSEG + 1)          // 24601
#define S_I    (SEGD_I + 1)               // 24 floats
#define DEN_I  (S_I + NSEG)               // 24

typedef __attribute__((address_space(1))) const void glb_t;
typedef __attribute__((address_space(3))) void lds_t;

// ---- phase 1: per-chunk 6-ROI histogram, 64-bit packed atomics -----------
__global__ __launch_bounds__(512) void hist_kernel(
    const float* __restrict__ pred, const float* __restrict__ tgt,
    const void* __restrict__ mask, int* __restrict__ ws) {
  __shared__ unsigned long long hp[NBINS];      // 8 KB pred hist
  __shared__ unsigned long long ht[NBINS];      // 8 KB tgt hist
  __shared__ __align__(16) int tile[3590];      // 14 KB tile + counts
  const int tid  = threadIdx.x;
  const int lane = tid & 63;
  const int wid  = tid >> 6;            // 8 waves
  const int flat = blockIdx.x;          // 0..1023
  const int b    = flat >> 8;           // patient
  const int nb   = flat & (BLKP - 1);
  const int v0   = nb * CHUNK;

  const unsigned int* mwp = (const unsigned int*)mask;
  const int byteLayout = __any(mwp[tid] > 1u);

  for (int i = tid; i < NBINS; i += 512) { hp[i] = 0ull; ht[i] = 0ull; }
  if (tid < 6) tile[T_CNT + tid] = 0;
  if (flat < 128 && tid < 193) {        // pre-zero dispatch-2 counters
    int zi = flat * 193 + tid;
    if (zi < ZERO_N) ws[ZERO_I + zi] = 0;
  }

  unsigned long long cpack = 0ull;      // per-thread packed mask counts

#define VOX(A, PP, GG)                                                       \
  {                                                                          \
    int bp = min((int)((PP) * 1024.0f), NB1);                                \
    int bg = min((int)((GG) * 1024.0f), NB1);                                \
    atomicAdd(&hp[bp], (A)); atomicAdd(&ht[bg], (A));                        \
    cpack += (A);                                                            \
  }

  if (byteLayout) {
    const char* pbase = (const char*)(pred + (size_t)b * VVOX + v0);
    const char* gbase = (const char*)(tgt  + (size_t)b * VVOX + v0);
    const char* mbase = (const char*)mask;

    for (int t = 0; t < NTILE; t++) {
      // DMA 14 x 1KB slices: 0-3 pred, 4-7 tgt, 8-13 masks (roi r = j-8)
      for (int j = wid; j < 14; j += 8) {
        const char* src; int dst;
        if (j < 4)      { src = pbase + t * 4096 + j * 1024;       dst = (T_PRED * 4) + j * 1024; }
        else if (j < 8) { src = gbase + t * 4096 + (j - 4) * 1024; dst = (T_TGT * 4) + (j - 4) * 1024; }
        else {
          int r = j - 8;
          src = mbase + (size_t)(r * BPAT + b) * VVOX + v0 + t * TILE;
          dst = (T_MSK * 4) + r * 1024;
        }
        __builtin_amdgcn_global_load_lds(
            (glb_t*)(src + lane * 16),
            (lds_t*)((char*)tile + dst), 16, 0, 0);
      }
      __syncthreads();   // drain DMA (hist-zero also visible on iter 0)

      // 2 voxels per thread: tile voxels 2*tid, 2*tid+1
      float2 pv = *(const float2*)&tile[T_PRED + 2 * tid];
      float2 gv = *(const float2*)&tile[T_TGT + 2 * tid];
      unsigned md[RROI];
#pragma unroll
      for (int r = 0; r < RROI; r++)
        md[r] = *(const unsigned*)&tile[T_MSK + r * 256 + (tid >> 1)];
      const int sh = (tid & 1) << 4;    // byte pair within the dword
      unsigned long long a0 = 0ull, a1 = 0ull;
#pragma unroll
      for (int r = 0; r < RROI; r++) {
        a0 |= (unsigned long long)((md[r] >> sh) & 1u) << (10 * r);
        a1 |= (unsigned long long)((md[r] >> (sh + 8)) & 1u) << (10 * r);
      }
      VOX(a0, pv.x, gv.x)
      VOX(a1, pv.y, gv.y)
      __syncthreads();   // protect tile before next DMA overwrites
    }
  } else {  // int32 masks — correctness-only path, direct loads
    __syncthreads();
    const int* mi = (const int*)mask;
    const float4* p4 = (const float4*)(pred + (size_t)b * VVOX + v0);
    const float4* g4 = (const float4*)(tgt  + (size_t)b * VVOX + v0);
    for (int pk = tid; pk < CHUNK / 4; pk += 512) {
      float4 pv = p4[pk], gv = g4[pk];
      unsigned long long a0 = 0, a1 = 0, a2 = 0, a3 = 0;
#pragma unroll
      for (int r = 0; r < RROI; r++) {
        int4 mm = ((const int4*)(mi + (size_t)(r * BPAT + b) * VVOX + v0))[pk];
        a0 |= (unsigned long long)(mm.x & 1) << (10 * r);
        a1 |= (unsigned long long)(mm.y & 1) << (10 * r);
        a2 |= (unsigned long long)(mm.z & 1) << (10 * r);
        a3 |= (unsigned long long)(mm.w & 1) << (10 * r);
      }
      VOX(a0, pv.x, gv.x)
      VOX(a1, pv.y, gv.y)
      VOX(a2, pv.z, gv.z)
      VOX(a3, pv.w, gv.w)
    }
    __syncthreads();
  }
#undef VOX

  // count merge: wave-reduce packed u64 (fields <= 8 voxels*64 lanes = 512,
  // 10-bit safe), lane 0 unpacks -> 6 int LDS atomics per wave
  for (int off = 32; off > 0; off >>= 1)
    cpack += __shfl_down(cpack, off, 64);
  if (lane == 0) {
#pragma unroll
    for (int r = 0; r < RROI; r++)
      atomicAdd(&tile[T_CNT + r], (int)((cpack >> (10 * r)) & 1023ull));
  }
  __syncthreads();

  // write signed int16 diffs (pred-tgt), 2 bins per int
  for (int idx = tid; idx < RROI * HW; idx += 512) {   // 6 iters
    int r = idx >> 9, wd = idx & (HW - 1);
    int s = 10 * r;
    int d0 = (int)((hp[2 * wd] >> s) & 1023ull) -
             (int)((ht[2 * wd] >> s) & 1023ull);
    int d1 = (int)((hp[2 * wd + 1] >> s) & 1023ull) -
             (int)((ht[2 * wd + 1] >> s) & 1023ull);
    ws[PART_I + (size_t)(flat * RROI + r) * HW + wd] = (d0 & 0xffff) | (d1 << 16);
  }
  if (tid < RROI)
    ws[CNT6_I + flat * RROI + tid] = tile[T_CNT + tid];
}

// ---- phase 2: reduce quarters -> global merge -> winner scan -> finalize -
__global__ __launch_bounds__(256) void seg_scan(int* __restrict__ ws,
                                                float* __restrict__ out) {
  const int bq  = blockIdx.x;          // 0..95
  const int seg = bq >> 2, q = bq & 3;
  const int r   = seg >> 2, b = seg & 3;
  const int t   = threadIdx.x;         // 256 threads; each owns bins 4t..4t+3

  int s[4] = {0, 0, 0, 0};
#pragma unroll 4
  for (int nb = q * 64; nb < q * 64 + 64; nb++) {   // 64 blocks per quarter
    const int2 wv = ((const int2*)(ws + PART_I +
                     (size_t)((b * BLKP + nb) * RROI + r) * HW))[t];
    s[0] += (int)(short)(wv.x & 0xffff); s[1] += wv.x >> 16;
    s[2] += (int)(short)(wv.y & 0xffff); s[3] += wv.y >> 16;
  }
  int* fh = ws + FH_I + seg * NBINS + 4 * t;
#pragma unroll
  for (int k = 0; k < 4; k++)
    if (s[k]) atomicAdd(&fh[k], s[k]);
  __threadfence();
  __shared__ int winflag;
  if (t == 0) winflag = (atomicAdd(ws + DONE_I + seg, 1) == 3);
  __syncthreads();
  if (!winflag) return;

  int bins[4];
#pragma unroll
  for (int k = 0; k < 4; k++)
    bins[k] = __hip_atomic_load(&fh[k], __ATOMIC_RELAXED,
                                __HIP_MEMORY_SCOPE_AGENT);
  // denominator: 256 per-block counts for this (roi, patient)
  int dv = ws[CNT6_I + (b * BLKP + t) * RROI + r];

  int tot = 0;
#pragma unroll
  for (int k = 0; k < 4; k++) { tot += bins[k]; bins[k] = tot; }
  const int lane = t & 63, wid = t >> 6;       // 4 waves
  int v = tot;
  for (int off = 1; off < 64; off <<= 1) {
    int u = __shfl_up(v, off, 64);
    if (lane >= off) v += u;
  }
  __shared__ int wsum[4]; __shared__ unsigned long long lsum[4];
  __shared__ int dsum[4];
  if (lane == 63) wsum[wid] = v;
  for (int off = 32; off > 0; off >>= 1) dv += __shfl_down(dv, off, 64);
  if (lane == 0) dsum[wid] = dv;
  __syncthreads();
  int woff = 0;
  for (int w = 0; w < wid; w++) woff += wsum[w];
  const int excl = woff + v - tot;
  unsigned long long acc = 0;
#pragma unroll
  for (int k = 0; k < 4; k++) {
    int c = excl + bins[k];
    acc += (unsigned long long)(c < 0 ? -c : c);
  }
  for (int off = 32; off > 0; off >>= 1) acc += __shfl_down(acc, off, 64);
  if (lane == 0) lsum[wid] = acc;
  __syncthreads();

  if (t == 0) {
    unsigned long long a = 0; int d = 0;
    for (int w = 0; w < 4; w++) { a += lsum[w]; d += dsum[w]; }
    ((float*)ws)[S_I + seg] = (float)((double)a * (52.0 / (double)NBINS));
    ws[DEN_I + seg] = d;
    __threadfence();
    if (atomicAdd(ws + SEGD_I, 1) == NSEG - 1) {   // last segment finalizes
      float total = 0.f; int nv = 0;
      for (int bb = 0; bb < BPAT; bb++) {
        float num = 0.f; long long dd = 0;
        for (int rr = 0; rr < RROI; rr++) {
          num += __hip_atomic_load(&((float*)ws)[S_I + rr * BPAT + bb],
                                   __ATOMIC_RELAXED, __HIP_MEMORY_SCOPE_AGENT);
          dd  += __hip_atomic_load(&ws[DEN_I + rr * BPAT + bb],
                                   __ATOMIC_RELAXED, __HIP_MEMORY_SCOPE_AGENT);
        }
        if (dd > 0) { total += num / fmaxf((float)dd, 1.f); nv++; }
      }
      out[0] = total / (float)(nv > 0 ? nv : 1);
    }
  }
}

extern "C" void kernel_launch(void* const* d_in, const int* in_sizes, int n_in,
                              void* d_out, int out_size, void* d_ws,
                              size_t ws_size, hipStream_t stream) {
  const float* pred = (const float*)d_in[0];
  const float* tgt  = (const float*)d_in[1];
  const void* mask  = d_in[2];
  int* ws = (int*)d_ws;   // needs ~12.8 MB; d_ws is 384 MiB

  hist_kernel<<<GRID1, 512, 0, stream>>>(pred, tgt, mask, ws);
  seg_scan<<<NSEG * 4, 256, 0, stream>>>(ws, (float*)d_out);
}